// Round 6
// baseline (278.714 us; speedup 1.0000x reference)
//
#include <hip/hip_runtime.h>
#include <cmath>

#define HDIM 2048
#define H4   (HDIM / 4)         // 512 float4 per row
#define NEXP 64
#define TTOT 16384
#define KSPLIT 2
#define KBLK (HDIM / KSPLIT)    // 1024 k per block
#define NSTEP (KBLK / 32)       // 32 K=32 MFMA steps
#define BTOK 64                 // tokens per block
#define LDS_SC 65

// ws layout (floats): [0..63] prob_acc, [64..127] gate_acc,
// [128 .. 128+PARTIAL) partials, then 3x gw bf16 split arrays (shorts).
#define WS_PARTIAL_OFF 128
#define PARTIAL_FLOATS ((size_t)(TTOT / BTOK) * KSPLIT * BTOK * NEXP)  // 2.1M
#define GWSZ (NEXP * HDIM)      // 131072 elements per split array

typedef short  bf16x8 __attribute__((ext_vector_type(8)));
typedef float  f32x4  __attribute__((ext_vector_type(4)));
typedef int    i32x4  __attribute__((ext_vector_type(4)));

// Exact 3-way truncation split: f == h + m + l bitwise (8+8+8 >= 24 mantissa
// bits; each residual is Sterbenz-exact). Packs 8 floats into 3 bf16x8 frags.
__device__ __forceinline__ void split8(const float4 f0, const float4 f1,
                                       bf16x8* h, bf16x8* m, bf16x8* l)
{
    const float f[8] = {f0.x, f0.y, f0.z, f0.w, f1.x, f1.y, f1.z, f1.w};
    unsigned uh[8], um[8], ul[8];
    #pragma unroll
    for (int i = 0; i < 8; ++i) {
        const unsigned u = __float_as_uint(f[i]);
        uh[i] = u & 0xffff0000u;
        const float r1 = f[i] - __uint_as_float(uh[i]);
        um[i] = __float_as_uint(r1) & 0xffff0000u;
        const float r2 = r1 - __uint_as_float(um[i]);
        ul[i] = __float_as_uint(r2) & 0xffff0000u;
    }
    i32x4 vh, vm, vl;
    #pragma unroll
    for (int j = 0; j < 4; ++j) {
        vh[j] = (int)((uh[2*j] >> 16) | uh[2*j+1]);   // low short = even k
        vm[j] = (int)((um[2*j] >> 16) | um[2*j+1]);
        vl[j] = (int)((ul[2*j] >> 16) | ul[2*j+1]);
    }
    *h = *reinterpret_cast<bf16x8*>(&vh);
    *m = *reinterpret_cast<bf16x8*>(&vm);
    *l = *reinterpret_cast<bf16x8*>(&vl);
}

// ===========================================================================
// Kernel 0: pre-split gw (64x2048 fp32) into h/m/l bf16 arrays, once.
// ===========================================================================
__global__ __launch_bounds__(256) void split_gw_kernel(
    const float* __restrict__ gw,
    short* __restrict__ gwh, short* __restrict__ gwm, short* __restrict__ gwl)
{
    const int g   = blockIdx.x * 256 + threadIdx.x;   // 0..16383 groups of 8
    const int idx = g * 8;
    const float4 f0 = *reinterpret_cast<const float4*>(gw + idx);
    const float4 f1 = *reinterpret_cast<const float4*>(gw + idx + 4);
    bf16x8 h, m, l;
    split8(f0, f1, &h, &m, &l);
    *reinterpret_cast<bf16x8*>(gwh + idx) = h;
    *reinterpret_cast<bf16x8*>(gwm + idx) = m;
    *reinterpret_cast<bf16x8*>(gwl + idx) = l;
}

// ===========================================================================
// Kernel 1: LDS-free streaming MFMA GEMM.
// Block = 64 tokens x 64 experts x K=1024 (grid 256 x 2), 4 waves, each wave
// a 32x32 quadrant = 2x2 tiles of v_mfma_f32_16x16x32_bf16, 6 split-products
// (hH,hM,mH,hL,mM,lH). A frags: global fp32 -> in-register split (each x elem
// read exactly once). B frags: direct 16B loads from pre-split gw (L2-hot).
// No LDS, no barriers.
// ===========================================================================
__global__ __launch_bounds__(256, 2) void router_gemm_mfma(
    const float* __restrict__ x,        // [T, H]
    const short* __restrict__ gwh,      // [E, H] bf16 high
    const short* __restrict__ gwm,      // [E, H] bf16 mid
    const short* __restrict__ gwl,      // [E, H] bf16 low
    float* __restrict__ partial)        // [256][2][64*64]
{
    const int tid  = threadIdx.x;
    const int lane = tid & 63;
    const int quad = lane >> 4;
    const int l15  = lane & 15;
    const int w    = tid >> 6;          // wave 0..3
    const int wm   = w & 1;             // token half
    const int wn   = w >> 1;            // expert half
    const int tb   = blockIdx.x;        // token block 0..255
    const int kg   = blockIdx.y;        // K half 0..1
    const int T0   = tb * BTOK;

    const float4* __restrict__ x4 = reinterpret_cast<const float4*>(x);

    // A row base (float4 units) per mt; frag k-offset quad*8 floats = quad*2 f4
    size_t arow[2];
    #pragma unroll
    for (int mt = 0; mt < 2; ++mt)
        arow[mt] = (size_t)(T0 + 32 * wm + 16 * mt + l15) * H4
                 + (size_t)kg * (H4 / 2) + quad * 2;

    // B row base (short units) per nt
    int brow[2];
    #pragma unroll
    for (int nt = 0; nt < 2; ++nt)
        brow[nt] = (32 * wn + 16 * nt + l15) * HDIM + kg * KBLK + quad * 8;

    f32x4 acc[2][2];
    #pragma unroll
    for (int i = 0; i < 2; ++i)
        #pragma unroll
        for (int j = 0; j < 2; ++j)
            acc[i][j] = (f32x4){0.f, 0.f, 0.f, 0.f};

    #pragma unroll 2
    for (int s = 0; s < NSTEP; ++s) {
        // B frags: 6 x 16B direct loads (L2-resident pre-split gw)
        bf16x8 bh[2], bm[2], bl[2];
        #pragma unroll
        for (int nt = 0; nt < 2; ++nt) {
            const int o = brow[nt] + s * 32;
            bh[nt] = *reinterpret_cast<const bf16x8*>(gwh + o);
            bm[nt] = *reinterpret_cast<const bf16x8*>(gwm + o);
            bl[nt] = *reinterpret_cast<const bf16x8*>(gwl + o);
        }
        // A frags: 4 x dwordx4 fp32 loads + in-register split
        bf16x8 ah[2], am[2], al[2];
        #pragma unroll
        for (int mt = 0; mt < 2; ++mt) {
            const float4 f0 = x4[arow[mt] + (size_t)s * 8];
            const float4 f1 = x4[arow[mt] + (size_t)s * 8 + 1];
            split8(f0, f1, &ah[mt], &am[mt], &al[mt]);
        }
        // 24 MFMAs
        #pragma unroll
        for (int mt = 0; mt < 2; ++mt)
            #pragma unroll
            for (int nt = 0; nt < 2; ++nt) {
                f32x4 c = acc[mt][nt];
                c = __builtin_amdgcn_mfma_f32_16x16x32_bf16(ah[mt], bh[nt], c, 0, 0, 0);
                c = __builtin_amdgcn_mfma_f32_16x16x32_bf16(ah[mt], bm[nt], c, 0, 0, 0);
                c = __builtin_amdgcn_mfma_f32_16x16x32_bf16(am[mt], bh[nt], c, 0, 0, 0);
                c = __builtin_amdgcn_mfma_f32_16x16x32_bf16(ah[mt], bl[nt], c, 0, 0, 0);
                c = __builtin_amdgcn_mfma_f32_16x16x32_bf16(am[mt], bm[nt], c, 0, 0, 0);
                c = __builtin_amdgcn_mfma_f32_16x16x32_bf16(al[mt], bh[nt], c, 0, 0, 0);
                acc[mt][nt] = c;
            }
    }

    // write fp32 partials (C/D layout: row = quad*4+reg, col = lane&15)
    float* pbase = partial + ((size_t)tb * KSPLIT + kg) * (BTOK * NEXP);
    #pragma unroll
    for (int mt = 0; mt < 2; ++mt)
        #pragma unroll
        for (int nt = 0; nt < 2; ++nt) {
            const int e = 32 * wn + 16 * nt + l15;
            #pragma unroll
            for (int r = 0; r < 4; ++r) {
                const int t_loc = 32 * wm + 16 * mt + quad * 4 + r;
                pbase[(size_t)t_loc * NEXP + e] = acc[mt][nt][r];
            }
        }
}

// ===========================================================================
// Kernel 2: sum 2 K-split partials + bias, top-2 + softmax + aux partials.
// ===========================================================================
__global__ __launch_bounds__(256) void router_reduce(
    const float* __restrict__ partial,
    const float* __restrict__ rep,
    const float* __restrict__ loads,
    const float* __restrict__ counts,
    const int*   __restrict__ total_dec,
    float* __restrict__ out_w,
    float* __restrict__ out_idx,
    float* __restrict__ prob_acc,
    float* __restrict__ gate_acc)
{
    __shared__ float sc_s[BTOK][LDS_SC];
    __shared__ float bias_s[NEXP];
    __shared__ float m_s[BTOK], z_s[BTOK];
    __shared__ int   i1_s[BTOK], i2_s[BTOK];

    const int tid = threadIdx.x;
    const int rt  = blockIdx.x;        // 64-token tile 0..255
    const int t0  = rt * BTOK;

    if (tid < NEXP) {
        float L = logf((float)(*total_dec) + 1.0f);
        bias_s[tid] = 0.1f * rep[tid] - 0.1f * loads[tid]
                    + 0.1f * sqrtf(L / (counts[tid] + 1e-10f));
    }
    __syncthreads();

    const float* p = partial + (size_t)rt * KSPLIT * (BTOK * NEXP);
    #pragma unroll
    for (int o = 0; o < (BTOK * NEXP) / 256; ++o) {
        const int idx = o * 256 + tid;
        float s = p[idx] + p[BTOK * NEXP + idx];
        sc_s[idx >> 6][idx & 63] = s + bias_s[idx & 63];
    }
    __syncthreads();

    // pass 1: per-token top-2 (strict '>' keeps lowest index), softmax weights
    if (tid < BTOK) {
        const int t = tid;
        float m1 = -INFINITY, m2 = -INFINITY;
        int   i1 = 0, i2 = 0;
        for (int e = 0; e < NEXP; ++e) {
            const float s = sc_s[t][e];
            if (s > m1)      { m2 = m1; i2 = i1; m1 = s; i1 = e; }
            else if (s > m2) { m2 = s; i2 = e; }
        }
        float z = 0.0f;
        for (int e = 0; e < NEXP; ++e) z += expf(sc_s[t][e] - m1);

        const float e2  = expf(m2 - m1);
        const float inv = 1.0f / (1.0f + e2);
        const int   gt  = t0 + t;
        reinterpret_cast<float2*>(out_w)[gt]   = make_float2(inv, e2 * inv);
        reinterpret_cast<float2*>(out_idx)[gt] = make_float2((float)i1, (float)i2);
        m_s[t] = m1; z_s[t] = z; i1_s[t] = i1; i2_s[t] = i2;
    }
    __syncthreads();

    // pass 2: per-expert partial sums for aux loss
    if (tid < NEXP) {
        const int e = tid;
        float ps = 0.0f, gs = 0.0f;
        for (int t = 0; t < BTOK; ++t) {
            ps += expf(sc_s[t][e] - m_s[t]) / z_s[t];
            gs += (float)((i1_s[t] == e) + (i2_s[t] == e));
        }
        atomicAdd(&prob_acc[e], ps);
        atomicAdd(&gate_acc[e], gs);
    }
}

// ===========================================================================
// Fallback (round-1/3 proven): single fused fp32 kernel, if ws too small.
// ===========================================================================
#define BKF  32
#define LDAF (64 + 4)
__global__ __launch_bounds__(256) void router_main(
    const float* __restrict__ x,
    const float* __restrict__ gw,
    const float* __restrict__ rep,
    const float* __restrict__ loads,
    const float* __restrict__ counts,
    const int*   __restrict__ total_dec,
    float* __restrict__ out_w,
    float* __restrict__ out_idx,
    float* __restrict__ prob_acc,
    float* __restrict__ gate_acc)
{
    __shared__ float a_s[2][BKF][LDAF];
    __shared__ float b_s[2][BKF][LDAF];
    __shared__ float sc_s[64][LDS_SC];
    __shared__ float bias_s[NEXP];
    __shared__ float m_s[64], z_s[64];
    __shared__ int   i1_s[64], i2_s[64];

    const int tid = threadIdx.x;
    const int tx  = tid & 15;
    const int ty  = tid >> 4;
    const int r0  = tid >> 3;
    const int c4  = tid & 7;
    const int t0  = blockIdx.x * 64;

    if (tid < NEXP) {
        float L = logf((float)(*total_dec) + 1.0f);
        bias_s[tid] = 0.1f * rep[tid] - 0.1f * loads[tid]
                    + 0.1f * sqrtf(L / (counts[tid] + 1e-10f));
    }

    const float4* __restrict__ x4 = reinterpret_cast<const float4*>(x) + (size_t)t0 * H4;
    const float4* __restrict__ g4 = reinterpret_cast<const float4*>(gw);

    float acc[4][4] = {};

#define STORE_TILE(BUFI, A0, A1, B0, B1) do {                                  \
        float _t0[4] = {(A0).x, (A0).y, (A0).z, (A0).w};                       \
        float _t1[4] = {(A1).x, (A1).y, (A1).z, (A1).w};                       \
        float _t2[4] = {(B0).x, (B0).y, (B0).z, (B0).w};                       \
        float _t3[4] = {(B1).x, (B1).y, (B1).z, (B1).w};                       \
        _Pragma("unroll")                                                      \
        for (int u = 0; u < 4; ++u) {                                          \
            a_s[BUFI][c4 * 4 + u][r0]      = _t0[u];                           \
            a_s[BUFI][c4 * 4 + u][r0 + 32] = _t1[u];                           \
            b_s[BUFI][c4 * 4 + u][r0]      = _t2[u];                           \
            b_s[BUFI][c4 * 4 + u][r0 + 32] = _t3[u];                           \
        } } while (0)

    {
        float4 a0 = x4[(size_t)r0 * H4 + c4];
        float4 a1 = x4[(size_t)(r0 + 32) * H4 + c4];
        float4 b0 = g4[(size_t)r0 * H4 + c4];
        float4 b1 = g4[(size_t)(r0 + 32) * H4 + c4];
        STORE_TILE(0, a0, a1, b0, b1);
    }
    __syncthreads();

    int buf = 0;
    for (int it = 0; it < HDIM / BKF; ++it) {
        float4 na0, na1, nb0, nb1;
        const bool has_next = (it + 1 < HDIM / BKF);
        if (has_next) {
            const int k4 = (it + 1) * (BKF / 4);
            na0 = x4[(size_t)r0 * H4 + k4 + c4];
            na1 = x4[(size_t)(r0 + 32) * H4 + k4 + c4];
            nb0 = g4[(size_t)r0 * H4 + k4 + c4];
            nb1 = g4[(size_t)(r0 + 32) * H4 + k4 + c4];
        }
        #pragma unroll
        for (int kk = 0; kk < BKF; ++kk) {
            const float4 afv = *reinterpret_cast<const float4*>(&a_s[buf][kk][ty * 4]);
            const float4 bfv = *reinterpret_cast<const float4*>(&b_s[buf][kk][tx * 4]);
            const float af[4] = {afv.x, afv.y, afv.z, afv.w};
            const float bf[4] = {bfv.x, bfv.y, bfv.z, bfv.w};
            #pragma unroll
            for (int i = 0; i < 4; ++i)
                #pragma unroll
                for (int j = 0; j < 4; ++j)
                    acc[i][j] = fmaf(af[i], bf[j], acc[i][j]);
        }
        if (has_next) STORE_TILE(buf ^ 1, na0, na1, nb0, nb1);
        __syncthreads();
        buf ^= 1;
    }
#undef STORE_TILE

    #pragma unroll
    for (int i = 0; i < 4; ++i)
        #pragma unroll
        for (int j = 0; j < 4; ++j)
            sc_s[ty * 4 + i][tx * 4 + j] = acc[i][j] + bias_s[tx * 4 + j];
    __syncthreads();

    if (tid < 64) {
        const int t = tid;
        float m1 = -INFINITY, m2 = -INFINITY;
        int   i1 = 0, i2 = 0;
        for (int e = 0; e < NEXP; ++e) {
            const float s = sc_s[t][e];
            if (s > m1)      { m2 = m1; i2 = i1; m1 = s; i1 = e; }
            else if (s > m2) { m2 = s; i2 = e; }
        }
        float z = 0.0f;
        for (int e = 0; e < NEXP; ++e) z += expf(sc_s[t][e] - m1);
        const float e2  = expf(m2 - m1);
        const float inv = 1.0f / (1.0f + e2);
        const int   gt  = t0 + t;
        reinterpret_cast<float2*>(out_w)[gt]   = make_float2(inv, e2 * inv);
        reinterpret_cast<float2*>(out_idx)[gt] = make_float2((float)i1, (float)i2);
        m_s[t] = m1; z_s[t] = z; i1_s[t] = i1; i2_s[t] = i2;
    }
    __syncthreads();

    if (tid < NEXP) {
        const int e = tid;
        float ps = 0.0f, gs = 0.0f;
        for (int t = 0; t < 64; ++t) {
            ps += expf(sc_s[t][e] - m_s[t]) / z_s[t];
            gs += (float)((i1_s[t] == e) + (i2_s[t] == e));
        }
        atomicAdd(&prob_acc[e], ps);
        atomicAdd(&gate_acc[e], gs);
    }
}

__global__ void router_aux(const float* __restrict__ prob_acc,
                           const float* __restrict__ gate_acc,
                           float* __restrict__ out_aux)
{
    const float invT = 1.0f / (float)TTOT;
    const int e = threadIdx.x;
    float v = (gate_acc[e] * invT) * (prob_acc[e] * invT);
    #pragma unroll
    for (int off = 32; off > 0; off >>= 1)
        v += __shfl_down(v, off);
    if (e == 0) out_aux[0] = v * (float)NEXP;
}

extern "C" void kernel_launch(void* const* d_in, const int* in_sizes, int n_in,
                              void* d_out, int out_size, void* d_ws, size_t ws_size,
                              hipStream_t stream)
{
    const float* x      = (const float*)d_in[0];
    const float* gw     = (const float*)d_in[1];
    const float* rep    = (const float*)d_in[2];
    const float* loads  = (const float*)d_in[3];
    const float* counts = (const float*)d_in[4];
    const int*   total  = (const int*)d_in[5];

    float* out     = (float*)d_out;
    float* out_w   = out;            // [16384*2] routing weights
    float* out_idx = out + 32768;    // [16384*2] expert indices as float
    float* out_aux = out + 65536;    // [1] aux loss

    float* prob_acc = (float*)d_ws;
    float* gate_acc = prob_acc + NEXP;
    float* partial  = (float*)d_ws + WS_PARTIAL_OFF;
    short* gwsplit  = (short*)((float*)d_ws + WS_PARTIAL_OFF + PARTIAL_FLOATS);
    short* gwh = gwsplit;
    short* gwm = gwsplit + GWSZ;
    short* gwl = gwsplit + 2 * GWSZ;

    const size_t ws_needed = (WS_PARTIAL_OFF + PARTIAL_FLOATS) * sizeof(float)
                           + 3 * GWSZ * sizeof(short);

    hipMemsetAsync(d_ws, 0, WS_PARTIAL_OFF * sizeof(float), stream);

    if (ws_size >= ws_needed) {
        split_gw_kernel<<<dim3(GWSZ / (256 * 8)), dim3(256), 0, stream>>>(gw, gwh, gwm, gwl);
        router_gemm_mfma<<<dim3(TTOT / BTOK, KSPLIT), dim3(256), 0, stream>>>(
            x, gwh, gwm, gwl, partial);
        router_reduce<<<dim3(TTOT / BTOK), dim3(256), 0, stream>>>(
            partial, rep, loads, counts, total, out_w, out_idx, prob_acc, gate_acc);
    } else {
        router_main<<<dim3(TTOT / 64), dim3(256), 0, stream>>>(
            x, gw, rep, loads, counts, total, out_w, out_idx, prob_acc, gate_acc);
    }
    router_aux<<<dim3(1), dim3(64), 0, stream>>>(prob_acc, gate_acc, out_aux);
}

// Round 7
// 272.460 us; speedup vs baseline: 1.0230x; 1.0230x over previous
//
#include <hip/hip_runtime.h>
#include <cmath>

#define HDIM 2048
#define H4   (HDIM / 4)         // 512 float4 per row
#define NEXP 64
#define TTOT 16384
#define KSPLIT 4
#define KBLK (HDIM / KSPLIT)    // 512 k per block
#define NSTEP (KBLK / 32)       // 16 K=32 MFMA steps
#define BTOK 64                 // tokens per block
#define LDS_SC 65

// ws layout (floats): [0..63] prob_acc, [64..127] gate_acc,
// [128 .. 128+PARTIAL) partials, then 3x gw bf16 split arrays (shorts).
#define WS_PARTIAL_OFF 128
#define PARTIAL_FLOATS ((size_t)(TTOT / BTOK) * KSPLIT * BTOK * NEXP)  // 4.2M
#define GWSZ (NEXP * HDIM)      // 131072 elements per split array

typedef short  bf16x8 __attribute__((ext_vector_type(8)));
typedef float  f32x4  __attribute__((ext_vector_type(4)));
typedef int    i32x4  __attribute__((ext_vector_type(4)));

// Exact 3-way truncation split: f == h + m + l bitwise (8+8+8 >= 24 mantissa
// bits; each residual is Sterbenz-exact). Packs 8 floats into 3 bf16x8 frags.
__device__ __forceinline__ void split8(const float4 f0, const float4 f1,
                                       bf16x8* h, bf16x8* m, bf16x8* l)
{
    const float f[8] = {f0.x, f0.y, f0.z, f0.w, f1.x, f1.y, f1.z, f1.w};
    unsigned uh[8], um[8], ul[8];
    #pragma unroll
    for (int i = 0; i < 8; ++i) {
        const unsigned u = __float_as_uint(f[i]);
        uh[i] = u & 0xffff0000u;
        const float r1 = f[i] - __uint_as_float(uh[i]);
        um[i] = __float_as_uint(r1) & 0xffff0000u;
        const float r2 = r1 - __uint_as_float(um[i]);
        ul[i] = __float_as_uint(r2) & 0xffff0000u;
    }
    i32x4 vh, vm, vl;
    #pragma unroll
    for (int j = 0; j < 4; ++j) {
        vh[j] = (int)((uh[2*j] >> 16) | uh[2*j+1]);   // low short = even k
        vm[j] = (int)((um[2*j] >> 16) | um[2*j+1]);
        vl[j] = (int)((ul[2*j] >> 16) | ul[2*j+1]);
    }
    *h = *reinterpret_cast<bf16x8*>(&vh);
    *m = *reinterpret_cast<bf16x8*>(&vm);
    *l = *reinterpret_cast<bf16x8*>(&vl);
}

// ===========================================================================
// Kernel 0: pre-split gw (64x2048 fp32) into h/m/l bf16 arrays, once.
// ===========================================================================
__global__ __launch_bounds__(256) void split_gw_kernel(
    const float* __restrict__ gw,
    short* __restrict__ gwh, short* __restrict__ gwm, short* __restrict__ gwl)
{
    const int g   = blockIdx.x * 256 + threadIdx.x;   // 0..16383 groups of 8
    const int idx = g * 8;
    const float4 f0 = *reinterpret_cast<const float4*>(gw + idx);
    const float4 f1 = *reinterpret_cast<const float4*>(gw + idx + 4);
    bf16x8 h, m, l;
    split8(f0, f1, &h, &m, &l);
    *reinterpret_cast<bf16x8*>(gwh + idx) = h;
    *reinterpret_cast<bf16x8*>(gwm + idx) = m;
    *reinterpret_cast<bf16x8*>(gwl + idx) = l;
}

// ===========================================================================
// Kernel 1: LDS-free streaming MFMA GEMM, depth-2 A prefetch, KSPLIT=4.
// Block = 64 tokens x 64 experts x K=512 (grid 256 x 4 -> 4 blocks/CU,
// 16 waves/CU). Each wave: 32x32 quadrant = 2x2 tiles of
// v_mfma_f32_16x16x32_bf16, 6 split-products (hH,hM,mH,hL,mM,lH).
// A: global fp32 -> in-register split, prefetched one step ahead (named regs,
// never arrays-by-ref -> no scratch demotion). B: direct 16B loads from
// pre-split gw (L2-hot). No LDS, no barriers.
// ===========================================================================
__global__ __launch_bounds__(256, 4) void router_gemm_mfma(
    const float* __restrict__ x,        // [T, H]
    const short* __restrict__ gwh,      // [E, H] bf16 high
    const short* __restrict__ gwm,      // [E, H] bf16 mid
    const short* __restrict__ gwl,      // [E, H] bf16 low
    float* __restrict__ partial)        // [256][4][64*64]
{
    const int tid  = threadIdx.x;
    const int lane = tid & 63;
    const int quad = lane >> 4;
    const int l15  = lane & 15;
    const int w    = tid >> 6;          // wave 0..3
    const int wm   = w & 1;             // token half
    const int wn   = w >> 1;            // expert half
    const int tb   = blockIdx.x;        // token block 0..255
    const int kg   = blockIdx.y;        // K quarter 0..3
    const int T0   = tb * BTOK;

    const float4* __restrict__ x4 = reinterpret_cast<const float4*>(x);

    // A row bases (float4 units); frag k-offset quad*8 floats = quad*2 f4
    const size_t arow0 = (size_t)(T0 + 32 * wm + l15) * H4
                       + (size_t)kg * (H4 / KSPLIT) + quad * 2;
    const size_t arow1 = arow0 + (size_t)16 * H4;

    // B row bases (short units)
    const int brow0 = (32 * wn + l15) * HDIM + kg * KBLK + quad * 8;
    const int brow1 = brow0 + 16 * HDIM;

    f32x4 acc00 = {0.f,0.f,0.f,0.f}, acc01 = {0.f,0.f,0.f,0.f};
    f32x4 acc10 = {0.f,0.f,0.f,0.f}, acc11 = {0.f,0.f,0.f,0.f};

    float4 p00, p01, p02, p03;   // A prefetch buffer 0 (mt0: p_0,p_1; mt1: p_2,p_3)
    float4 q00, q01, q02, q03;   // A prefetch buffer 1

#define LOADA(S, R0, R1, R2, R3) do {                                          \
        R0 = x4[arow0 + (size_t)(S) * 8];                                      \
        R1 = x4[arow0 + (size_t)(S) * 8 + 1];                                  \
        R2 = x4[arow1 + (size_t)(S) * 8];                                      \
        R3 = x4[arow1 + (size_t)(S) * 8 + 1];                                  \
    } while (0)

#define COMPUTE(S, R0, R1, R2, R3) do {                                        \
        const int _o0 = brow0 + (S) * 32;                                      \
        const int _o1 = brow1 + (S) * 32;                                      \
        const bf16x8 bh0 = *reinterpret_cast<const bf16x8*>(gwh + _o0);        \
        const bf16x8 bh1 = *reinterpret_cast<const bf16x8*>(gwh + _o1);        \
        const bf16x8 bm0 = *reinterpret_cast<const bf16x8*>(gwm + _o0);        \
        const bf16x8 bm1 = *reinterpret_cast<const bf16x8*>(gwm + _o1);        \
        const bf16x8 bl0 = *reinterpret_cast<const bf16x8*>(gwl + _o0);        \
        const bf16x8 bl1 = *reinterpret_cast<const bf16x8*>(gwl + _o1);        \
        bf16x8 ah0, am0, al0, ah1, am1, al1;                                   \
        split8(R0, R1, &ah0, &am0, &al0);                                      \
        split8(R2, R3, &ah1, &am1, &al1);                                      \
        acc00 = __builtin_amdgcn_mfma_f32_16x16x32_bf16(ah0, bh0, acc00, 0,0,0);\
        acc00 = __builtin_amdgcn_mfma_f32_16x16x32_bf16(ah0, bm0, acc00, 0,0,0);\
        acc00 = __builtin_amdgcn_mfma_f32_16x16x32_bf16(am0, bh0, acc00, 0,0,0);\
        acc00 = __builtin_amdgcn_mfma_f32_16x16x32_bf16(ah0, bl0, acc00, 0,0,0);\
        acc00 = __builtin_amdgcn_mfma_f32_16x16x32_bf16(am0, bm0, acc00, 0,0,0);\
        acc00 = __builtin_amdgcn_mfma_f32_16x16x32_bf16(al0, bh0, acc00, 0,0,0);\
        acc01 = __builtin_amdgcn_mfma_f32_16x16x32_bf16(ah0, bh1, acc01, 0,0,0);\
        acc01 = __builtin_amdgcn_mfma_f32_16x16x32_bf16(ah0, bm1, acc01, 0,0,0);\
        acc01 = __builtin_amdgcn_mfma_f32_16x16x32_bf16(am0, bh1, acc01, 0,0,0);\
        acc01 = __builtin_amdgcn_mfma_f32_16x16x32_bf16(ah0, bl1, acc01, 0,0,0);\
        acc01 = __builtin_amdgcn_mfma_f32_16x16x32_bf16(am0, bm1, acc01, 0,0,0);\
        acc01 = __builtin_amdgcn_mfma_f32_16x16x32_bf16(al0, bh1, acc01, 0,0,0);\
        acc10 = __builtin_amdgcn_mfma_f32_16x16x32_bf16(ah1, bh0, acc10, 0,0,0);\
        acc10 = __builtin_amdgcn_mfma_f32_16x16x32_bf16(ah1, bm0, acc10, 0,0,0);\
        acc10 = __builtin_amdgcn_mfma_f32_16x16x32_bf16(am1, bh0, acc10, 0,0,0);\
        acc10 = __builtin_amdgcn_mfma_f32_16x16x32_bf16(ah1, bl0, acc10, 0,0,0);\
        acc10 = __builtin_amdgcn_mfma_f32_16x16x32_bf16(am1, bm0, acc10, 0,0,0);\
        acc10 = __builtin_amdgcn_mfma_f32_16x16x32_bf16(al1, bh0, acc10, 0,0,0);\
        acc11 = __builtin_amdgcn_mfma_f32_16x16x32_bf16(ah1, bh1, acc11, 0,0,0);\
        acc11 = __builtin_amdgcn_mfma_f32_16x16x32_bf16(ah1, bm1, acc11, 0,0,0);\
        acc11 = __builtin_amdgcn_mfma_f32_16x16x32_bf16(am1, bh1, acc11, 0,0,0);\
        acc11 = __builtin_amdgcn_mfma_f32_16x16x32_bf16(ah1, bl1, acc11, 0,0,0);\
        acc11 = __builtin_amdgcn_mfma_f32_16x16x32_bf16(am1, bm1, acc11, 0,0,0);\
        acc11 = __builtin_amdgcn_mfma_f32_16x16x32_bf16(al1, bh1, acc11, 0,0,0);\
    } while (0)

    LOADA(0, p00, p01, p02, p03);

    #pragma unroll
    for (int s = 0; s < NSTEP; s += 2) {
        if (s + 1 < NSTEP) LOADA(s + 1, q00, q01, q02, q03);
        COMPUTE(s, p00, p01, p02, p03);
        if (s + 2 < NSTEP) LOADA(s + 2, p00, p01, p02, p03);
        COMPUTE(s + 1, q00, q01, q02, q03);
    }
#undef LOADA
#undef COMPUTE

    // write fp32 partials (C/D layout: row = quad*4+reg, col = lane&15)
    float* pbase = partial + ((size_t)tb * KSPLIT + kg) * (BTOK * NEXP);
    const int e0 = 32 * wn + l15;
    #pragma unroll
    for (int r = 0; r < 4; ++r) {
        const int tr0 = 32 * wm + quad * 4 + r;
        pbase[(size_t)tr0 * NEXP + e0]             = acc00[r];
        pbase[(size_t)tr0 * NEXP + e0 + 16]        = acc01[r];
        pbase[(size_t)(tr0 + 16) * NEXP + e0]      = acc10[r];
        pbase[(size_t)(tr0 + 16) * NEXP + e0 + 16] = acc11[r];
    }
}

// ===========================================================================
// Kernel 2: sum 4 K-split partials + bias, top-2 + softmax + aux partials.
// ===========================================================================
__global__ __launch_bounds__(256) void router_reduce(
    const float* __restrict__ partial,
    const float* __restrict__ rep,
    const float* __restrict__ loads,
    const float* __restrict__ counts,
    const int*   __restrict__ total_dec,
    float* __restrict__ out_w,
    float* __restrict__ out_idx,
    float* __restrict__ prob_acc,
    float* __restrict__ gate_acc)
{
    __shared__ float sc_s[BTOK][LDS_SC];
    __shared__ float bias_s[NEXP];
    __shared__ float m_s[BTOK], z_s[BTOK];
    __shared__ int   i1_s[BTOK], i2_s[BTOK];

    const int tid = threadIdx.x;
    const int rt  = blockIdx.x;        // 64-token tile 0..255
    const int t0  = rt * BTOK;

    if (tid < NEXP) {
        float L = logf((float)(*total_dec) + 1.0f);
        bias_s[tid] = 0.1f * rep[tid] - 0.1f * loads[tid]
                    + 0.1f * sqrtf(L / (counts[tid] + 1e-10f));
    }
    __syncthreads();

    const float* p = partial + (size_t)rt * KSPLIT * (BTOK * NEXP);
    #pragma unroll
    for (int o = 0; o < (BTOK * NEXP) / 256; ++o) {
        const int idx = o * 256 + tid;
        float s = 0.0f;
        #pragma unroll
        for (int g = 0; g < KSPLIT; ++g)
            s += p[(size_t)g * (BTOK * NEXP) + idx];
        sc_s[idx >> 6][idx & 63] = s + bias_s[idx & 63];
    }
    __syncthreads();

    // pass 1: per-token top-2 (strict '>' keeps lowest index), softmax weights
    if (tid < BTOK) {
        const int t = tid;
        float m1 = -INFINITY, m2 = -INFINITY;
        int   i1 = 0, i2 = 0;
        for (int e = 0; e < NEXP; ++e) {
            const float s = sc_s[t][e];
            if (s > m1)      { m2 = m1; i2 = i1; m1 = s; i1 = e; }
            else if (s > m2) { m2 = s; i2 = e; }
        }
        float z = 0.0f;
        for (int e = 0; e < NEXP; ++e) z += expf(sc_s[t][e] - m1);

        const float e2  = expf(m2 - m1);
        const float inv = 1.0f / (1.0f + e2);
        const int   gt  = t0 + t;
        reinterpret_cast<float2*>(out_w)[gt]   = make_float2(inv, e2 * inv);
        reinterpret_cast<float2*>(out_idx)[gt] = make_float2((float)i1, (float)i2);
        m_s[t] = m1; z_s[t] = z; i1_s[t] = i1; i2_s[t] = i2;
    }
    __syncthreads();

    // pass 2: per-expert partial sums for aux loss
    if (tid < NEXP) {
        const int e = tid;
        float ps = 0.0f, gs = 0.0f;
        for (int t = 0; t < BTOK; ++t) {
            ps += expf(sc_s[t][e] - m_s[t]) / z_s[t];
            gs += (float)((i1_s[t] == e) + (i2_s[t] == e));
        }
        atomicAdd(&prob_acc[e], ps);
        atomicAdd(&gate_acc[e], gs);
    }
}

// ===========================================================================
// Fallback (round-1/3 proven): single fused fp32 kernel, if ws too small.
// ===========================================================================
#define BKF  32
#define LDAF (64 + 4)
__global__ __launch_bounds__(256) void router_main(
    const float* __restrict__ x,
    const float* __restrict__ gw,
    const float* __restrict__ rep,
    const float* __restrict__ loads,
    const float* __restrict__ counts,
    const int*   __restrict__ total_dec,
    float* __restrict__ out_w,
    float* __restrict__ out_idx,
    float* __restrict__ prob_acc,
    float* __restrict__ gate_acc)
{
    __shared__ float a_s[2][BKF][LDAF];
    __shared__ float b_s[2][BKF][LDAF];
    __shared__ float sc_s[64][LDS_SC];
    __shared__ float bias_s[NEXP];
    __shared__ float m_s[64], z_s[64];
    __shared__ int   i1_s[64], i2_s[64];

    const int tid = threadIdx.x;
    const int tx  = tid & 15;
    const int ty  = tid >> 4;
    const int r0  = tid >> 3;
    const int c4  = tid & 7;
    const int t0  = blockIdx.x * 64;

    if (tid < NEXP) {
        float L = logf((float)(*total_dec) + 1.0f);
        bias_s[tid] = 0.1f * rep[tid] - 0.1f * loads[tid]
                    + 0.1f * sqrtf(L / (counts[tid] + 1e-10f));
    }

    const float4* __restrict__ x4 = reinterpret_cast<const float4*>(x) + (size_t)t0 * H4;
    const float4* __restrict__ g4 = reinterpret_cast<const float4*>(gw);

    float acc[4][4] = {};

#define STORE_TILE(BUFI, A0, A1, B0, B1) do {                                  \
        float _t0[4] = {(A0).x, (A0).y, (A0).z, (A0).w};                       \
        float _t1[4] = {(A1).x, (A1).y, (A1).z, (A1).w};                       \
        float _t2[4] = {(B0).x, (B0).y, (B0).z, (B0).w};                       \
        float _t3[4] = {(B1).x, (B1).y, (B1).z, (B1).w};                       \
        _Pragma("unroll")                                                      \
        for (int u = 0; u < 4; ++u) {                                          \
            a_s[BUFI][c4 * 4 + u][r0]      = _t0[u];                           \
            a_s[BUFI][c4 * 4 + u][r0 + 32] = _t1[u];                           \
            b_s[BUFI][c4 * 4 + u][r0]      = _t2[u];                           \
            b_s[BUFI][c4 * 4 + u][r0 + 32] = _t3[u];                           \
        } } while (0)

    {
        float4 a0 = x4[(size_t)r0 * H4 + c4];
        float4 a1 = x4[(size_t)(r0 + 32) * H4 + c4];
        float4 b0 = g4[(size_t)r0 * H4 + c4];
        float4 b1 = g4[(size_t)(r0 + 32) * H4 + c4];
        STORE_TILE(0, a0, a1, b0, b1);
    }
    __syncthreads();

    int buf = 0;
    for (int it = 0; it < HDIM / BKF; ++it) {
        float4 na0, na1, nb0, nb1;
        const bool has_next = (it + 1 < HDIM / BKF);
        if (has_next) {
            const int k4 = (it + 1) * (BKF / 4);
            na0 = x4[(size_t)r0 * H4 + k4 + c4];
            na1 = x4[(size_t)(r0 + 32) * H4 + k4 + c4];
            nb0 = g4[(size_t)r0 * H4 + k4 + c4];
            nb1 = g4[(size_t)(r0 + 32) * H4 + k4 + c4];
        }
        #pragma unroll
        for (int kk = 0; kk < BKF; ++kk) {
            const float4 afv = *reinterpret_cast<const float4*>(&a_s[buf][kk][ty * 4]);
            const float4 bfv = *reinterpret_cast<const float4*>(&b_s[buf][kk][tx * 4]);
            const float af[4] = {afv.x, afv.y, afv.z, afv.w};
            const float bf[4] = {bfv.x, bfv.y, bfv.z, bfv.w};
            #pragma unroll
            for (int i = 0; i < 4; ++i)
                #pragma unroll
                for (int j = 0; j < 4; ++j)
                    acc[i][j] = fmaf(af[i], bf[j], acc[i][j]);
        }
        if (has_next) STORE_TILE(buf ^ 1, na0, na1, nb0, nb1);
        __syncthreads();
        buf ^= 1;
    }
#undef STORE_TILE

    #pragma unroll
    for (int i = 0; i < 4; ++i)
        #pragma unroll
        for (int j = 0; j < 4; ++j)
            sc_s[ty * 4 + i][tx * 4 + j] = acc[i][j] + bias_s[tx * 4 + j];
    __syncthreads();

    if (tid < 64) {
        const int t = tid;
        float m1 = -INFINITY, m2 = -INFINITY;
        int   i1 = 0, i2 = 0;
        for (int e = 0; e < NEXP; ++e) {
            const float s = sc_s[t][e];
            if (s > m1)      { m2 = m1; i2 = i1; m1 = s; i1 = e; }
            else if (s > m2) { m2 = s; i2 = e; }
        }
        float z = 0.0f;
        for (int e = 0; e < NEXP; ++e) z += expf(sc_s[t][e] - m1);
        const float e2  = expf(m2 - m1);
        const float inv = 1.0f / (1.0f + e2);
        const int   gt  = t0 + t;
        reinterpret_cast<float2*>(out_w)[gt]   = make_float2(inv, e2 * inv);
        reinterpret_cast<float2*>(out_idx)[gt] = make_float2((float)i1, (float)i2);
        m_s[t] = m1; z_s[t] = z; i1_s[t] = i1; i2_s[t] = i2;
    }
    __syncthreads();

    if (tid < NEXP) {
        const int e = tid;
        float ps = 0.0f, gs = 0.0f;
        for (int t = 0; t < 64; ++t) {
            ps += expf(sc_s[t][e] - m_s[t]) / z_s[t];
            gs += (float)((i1_s[t] == e) + (i2_s[t] == e));
        }
        atomicAdd(&prob_acc[e], ps);
        atomicAdd(&gate_acc[e], gs);
    }
}

__global__ void router_aux(const float* __restrict__ prob_acc,
                           const float* __restrict__ gate_acc,
                           float* __restrict__ out_aux)
{
    const float invT = 1.0f / (float)TTOT;
    const int e = threadIdx.x;
    float v = (gate_acc[e] * invT) * (prob_acc[e] * invT);
    #pragma unroll
    for (int off = 32; off > 0; off >>= 1)
        v += __shfl_down(v, off);
    if (e == 0) out_aux[0] = v * (float)NEXP;
}

extern "C" void kernel_launch(void* const* d_in, const int* in_sizes, int n_in,
                              void* d_out, int out_size, void* d_ws, size_t ws_size,
                              hipStream_t stream)
{
    const float* x      = (const float*)d_in[0];
    const float* gw     = (const float*)d_in[1];
    const float* rep    = (const float*)d_in[2];
    const float* loads  = (const float*)d_in[3];
    const float* counts = (const float*)d_in[4];
    const int*   total  = (const int*)d_in[5];

    float* out     = (float*)d_out;
    float* out_w   = out;            // [16384*2] routing weights
    float* out_idx = out + 32768;    // [16384*2] expert indices as float
    float* out_aux = out + 65536;    // [1] aux loss

    float* prob_acc = (float*)d_ws;
    float* gate_acc = prob_acc + NEXP;
    float* partial  = (float*)d_ws + WS_PARTIAL_OFF;
    short* gwsplit  = (short*)((float*)d_ws + WS_PARTIAL_OFF + PARTIAL_FLOATS);
    short* gwh = gwsplit;
    short* gwm = gwsplit + GWSZ;
    short* gwl = gwsplit + 2 * GWSZ;

    const size_t ws_needed = (WS_PARTIAL_OFF + PARTIAL_FLOATS) * sizeof(float)
                           + 3 * GWSZ * sizeof(short);

    hipMemsetAsync(d_ws, 0, WS_PARTIAL_OFF * sizeof(float), stream);

    if (ws_size >= ws_needed) {
        split_gw_kernel<<<dim3(GWSZ / (256 * 8)), dim3(256), 0, stream>>>(gw, gwh, gwm, gwl);
        router_gemm_mfma<<<dim3(TTOT / BTOK, KSPLIT), dim3(256), 0, stream>>>(
            x, gwh, gwm, gwl, partial);
        router_reduce<<<dim3(TTOT / BTOK), dim3(256), 0, stream>>>(
            partial, rep, loads, counts, total, out_w, out_idx, prob_acc, gate_acc);
    } else {
        router_main<<<dim3(TTOT / 64), dim3(256), 0, stream>>>(
            x, gw, rep, loads, counts, total, out_w, out_idx, prob_acc, gate_acc);
    }
    router_aux<<<dim3(1), dim3(64), 0, stream>>>(prob_acc, gate_acc, out_aux);
}